// Round 1
// baseline (64.741 us; speedup 1.0000x reference)
//
#include <hip/hip_runtime.h>

// HardEMQuantizer forward:
//   logits:     (B=8, T=2048, M*K=4096) fp32  -> N = B*T = 16384 rows, M=8 splits, K=512 codes
//   embeddings: (M=8, K=512, D=64) fp32
// Outputs (concatenated flat, all read back as fp32):
//   [0 .. 8388608)        quantized      (B,T,M*D)  = gather of embedding rows
//   [8388608 .. 16777216) quantized_stack (B,T,M,D) = same flat data
//   [16777216 .. 16908288) encoding_indices (B,T,M)  = argmax index, written as float
//
// Forward value of straight-through z is exactly one_hot(argmax) (up to 1 ulp on the
// hot position), so the einsum collapses to a row gather. argmax(softmax(x)) == argmax(x).

#define MM 8
#define KK 512
#define DD 64

__global__ __launch_bounds__(256) void hardem_fwd(
    const float* __restrict__ logits,   // (N*M, K) contiguous
    const float* __restrict__ emb,      // (M, K, D)
    float* __restrict__ out,
    int n_tasks)                        // N*M = 131072
{
    const int wave = threadIdx.x >> 6;
    const int lane = threadIdx.x & 63;
    const int task = blockIdx.x * 4 + wave;
    if (task >= n_tasks) return;

    const int m = task & (MM - 1);                 // task = n*M + m
    const float* src = logits + (size_t)task * KK;

    // Each lane reads 8 contiguous floats as 2x float4.
    // float4 j covers k = 4j..4j+3; lanes 0..63 -> k 0..255, then 256..511.
    const float4* src4 = (const float4*)src;
    float4 a = src4[lane];
    float4 b = src4[64 + lane];

    // In-lane argmax with first-index tie-break (strict > keeps earlier k).
    int k0 = lane * 4;
    float best = a.x; int bidx = k0;
    if (a.y > best) { best = a.y; bidx = k0 + 1; }
    if (a.z > best) { best = a.z; bidx = k0 + 2; }
    if (a.w > best) { best = a.w; bidx = k0 + 3; }
    int k1 = 256 + lane * 4;
    if (b.x > best) { best = b.x; bidx = k1;     }
    if (b.y > best) { best = b.y; bidx = k1 + 1; }
    if (b.z > best) { best = b.z; bidx = k1 + 2; }
    if (b.w > best) { best = b.w; bidx = k1 + 3; }

    // Wave-wide butterfly reduce over 64 lanes; ties -> smaller k.
    #pragma unroll
    for (int mask = 1; mask < 64; mask <<= 1) {
        float oval = __shfl_xor(best, mask, 64);
        int   oidx = __shfl_xor(bidx, mask, 64);
        if (oval > best || (oval == best && oidx < bidx)) {
            best = oval;
            bidx = oidx;
        }
    }

    // Gather embedding row (M,K,D): 64 lanes read 64 contiguous floats.
    const float* erow = emb + ((size_t)m * KK + (size_t)bidx) * DD;
    float e = erow[lane];

    const size_t qoff = (size_t)task * DD + lane;
    out[qoff]           = e;                       // quantized
    out[8388608 + qoff] = e;                       // quantized_stack (same flat data)
    if (lane == 0)
        out[16777216 + (size_t)task] = (float)bidx; // encoding_indices as float
}

extern "C" void kernel_launch(void* const* d_in, const int* in_sizes, int n_in,
                              void* d_out, int out_size, void* d_ws, size_t ws_size,
                              hipStream_t stream) {
    const float* logits = (const float*)d_in[0];
    const float* emb    = (const float*)d_in[1];
    float* out          = (float*)d_out;

    const int n_tasks = 16384 * MM;                // N * M = 131072
    const int blocks  = n_tasks / 4;               // 4 waves (tasks) per 256-thread block

    hardem_fwd<<<blocks, 256, 0, stream>>>(logits, emb, out, n_tasks);
}

// Round 2
// 58.546 us; speedup vs baseline: 1.1058x; 1.1058x over previous
//
#include <hip/hip_runtime.h>

// HardEMQuantizer forward:
//   logits:     (B=8, T=2048, M*K=4096) fp32  -> N = B*T = 16384 rows, M=8 splits, K=512 codes
//   embeddings: (M=8, K=512, D=64) fp32
// Outputs (concatenated flat, all fp32):
//   [0 .. 8388608)        quantized        = gather of argmax embedding rows
//   [8388608 .. 16777216) quantized_stack  = same flat data
//   [16777216 .. 16908288) encoding_indices = argmax index as float
//
// Forward value of straight-through z is exactly one_hot(argmax), so the einsum
// collapses to a row gather; argmax(softmax(x)) == argmax(x).
//
// R2: 2 tasks per wave (4 independent logit loads in flight), non-temporal
// loads/stores (streaming data, no reuse), coalesced index stores.

#define MM 8
#define KK 512
#define DD 64

typedef float f32x4 __attribute__((ext_vector_type(4)));

__device__ inline void task_argmax(f32x4 a, f32x4 b, int lane, float& best, int& bidx) {
    int k0 = lane * 4;
    best = a.x; bidx = k0;
    if (a.y > best) { best = a.y; bidx = k0 + 1; }
    if (a.z > best) { best = a.z; bidx = k0 + 2; }
    if (a.w > best) { best = a.w; bidx = k0 + 3; }
    int k1 = 256 + lane * 4;
    if (b.x > best) { best = b.x; bidx = k1;     }
    if (b.y > best) { best = b.y; bidx = k1 + 1; }
    if (b.z > best) { best = b.z; bidx = k1 + 2; }
    if (b.w > best) { best = b.w; bidx = k1 + 3; }
}

__global__ __launch_bounds__(256) void hardem_fwd(
    const float* __restrict__ logits,   // (N*M, K) contiguous
    const float* __restrict__ emb,      // (M, K, D)
    float* __restrict__ out)
{
    const int wave = threadIdx.x >> 6;
    const int lane = threadIdx.x & 63;
    const int wid  = blockIdx.x * 4 + wave;
    const int t0   = wid * 2;           // two adjacent tasks per wave
    const int t1   = t0 + 1;

    // 4 independent coalesced 1 KiB loads (2 KiB logits per task), issued up front.
    const f32x4* s0 = (const f32x4*)(logits + (size_t)t0 * KK);
    const f32x4* s1 = (const f32x4*)(logits + (size_t)t1 * KK);
    f32x4 a0 = __builtin_nontemporal_load(&s0[lane]);
    f32x4 b0 = __builtin_nontemporal_load(&s0[64 + lane]);
    f32x4 a1 = __builtin_nontemporal_load(&s1[lane]);
    f32x4 b1 = __builtin_nontemporal_load(&s1[64 + lane]);

    // In-lane argmax (first-index tie-break via strict >), then 64-lane butterfly.
    float v0, v1; int i0, i1;
    task_argmax(a0, b0, lane, v0, i0);
    task_argmax(a1, b1, lane, v1, i1);

    #pragma unroll
    for (int mask = 1; mask < 64; mask <<= 1) {
        float o0 = __shfl_xor(v0, mask, 64);
        int   j0 = __shfl_xor(i0, mask, 64);
        float o1 = __shfl_xor(v1, mask, 64);
        int   j1 = __shfl_xor(i1, mask, 64);
        if (o0 > v0 || (o0 == v0 && j0 < i0)) { v0 = o0; i0 = j0; }
        if (o1 > v1 || (o1 == v1 && j1 < i1)) { v1 = o1; i1 = j1; }
    }
    // butterfly leaves the final (max, idx) replicated in every lane

    const int m0 = t0 & (MM - 1);
    const int m1 = t1 & (MM - 1);

    // Two independent embedding-row gathers (emb is 1 MiB -> L2-resident).
    float e0 = emb[((size_t)m0 * KK + (size_t)i0) * DD + lane];
    float e1 = emb[((size_t)m1 * KK + (size_t)i1) * DD + lane];

    const size_t q0 = (size_t)t0 * DD + lane;
    const size_t q1 = (size_t)t1 * DD + lane;
    __builtin_nontemporal_store(e0, &out[q0]);                 // quantized
    __builtin_nontemporal_store(e1, &out[q1]);
    __builtin_nontemporal_store(e0, &out[8388608 + q0]);       // quantized_stack
    __builtin_nontemporal_store(e1, &out[8388608 + q1]);

    // encoding_indices: lanes 0,1 write two contiguous floats.
    if (lane < 2)
        out[16777216 + (size_t)t0 + lane] = (float)(lane ? i1 : i0);
}

extern "C" void kernel_launch(void* const* d_in, const int* in_sizes, int n_in,
                              void* d_out, int out_size, void* d_ws, size_t ws_size,
                              hipStream_t stream) {
    const float* logits = (const float*)d_in[0];
    const float* emb    = (const float*)d_in[1];
    float* out          = (float*)d_out;

    // N*M = 131072 tasks, 2 per wave, 4 waves per block -> 16384 blocks
    hardem_fwd<<<16384, 256, 0, stream>>>(logits, emb, out);
}